// Round 26
// baseline (764.843 us; speedup 1.0000x reference)
//
#include <hip/hip_runtime.h>
#include <hip/hip_bf16.h>
#include <hip/hip_fp16.h>

#define B_    64
#define NO_   128
#define NR_   512
#define RNN_  1000
#define DIM_  1024

typedef short short8 __attribute__((ext_vector_type(8)));   // 8 bf16 (4 VGPRs)
typedef float f32x4  __attribute__((ext_vector_type(4)));
typedef float f32x2v __attribute__((ext_vector_type(2)));
typedef float f32x4v __attribute__((ext_vector_type(4)));

static __device__ __forceinline__ float bf2f(unsigned short u) {
    union { unsigned int i; float f; } x; x.i = ((unsigned int)u) << 16; return x.f;
}
static __device__ __forceinline__ short f2bf_s(float f) {
    __hip_bfloat16 h = __float2bfloat16(f);
    return *reinterpret_cast<short*>(&h);
}

#define GLOAD_LDS16(gp, lp) \
    __builtin_amdgcn_global_load_lds((const __attribute__((address_space(1))) void*)(gp), \
                                     (__attribute__((address_space(3))) void*)(lp), 16, 0, 0)

// ---------------- K1: obj_embed = relu(cat[relu(box@Wf+b), relu(emb[label])] @ Wcat + b) -> bf16 -------
__global__ void k_obj_embed(const int* __restrict__ labels,
                            const float* __restrict__ box_feats,
                            const float* __restrict__ emb_table,
                            const float* __restrict__ w_objfeat, const float* __restrict__ b_objfeat,
                            const float* __restrict__ w_cat, const float* __restrict__ b_cat,
                            __hip_bfloat16* __restrict__ out)
{
    const int row = blockIdx.x;      // b*NO + n
    const int tid = threadIdx.x;     // 0..127
    __shared__ __align__(16) float cat[256];
    __shared__ float bf[5];
    if (tid < 5) bf[tid] = box_feats[row * 5 + tid];
    __syncthreads();
    float acc = b_objfeat[tid];
#pragma unroll
    for (int k = 0; k < 5; ++k) acc += bf[k] * w_objfeat[k * 128 + tid];
    cat[tid] = fmaxf(acc, 0.f);
    const int label = labels[row];
    cat[128 + tid] = fmaxf(emb_table[label * 128 + tid], 0.f);
    __syncthreads();
    float acc2 = b_cat[tid];
#pragma unroll 4
    for (int k4 = 0; k4 < 64; ++k4) {
        const f32x4 c4 = *(const f32x4*)&cat[k4 * 4];
        acc2 += c4[0] * w_cat[(k4 * 4 + 0) * 128 + tid];
        acc2 += c4[1] * w_cat[(k4 * 4 + 1) * 128 + tid];
        acc2 += c4[2] * w_cat[(k4 * 4 + 2) * 128 + tid];
        acc2 += c4[3] * w_cat[(k4 * 4 + 3) * 128 + tid];
    }
    out[(size_t)row * 128 + tid] = __float2bfloat16(fmaxf(acc2, 0.f));
}

// ---------------- tiled transpose-convert: Wt[n][k] = bf16(W[k][n]), zero-padded to [Npad][Kpad] -------
__global__ void k_transpose(const float* __restrict__ W, __hip_bfloat16* __restrict__ Wt,
                            int K, int N, int ldn, int Kpad)
{
    __shared__ float t[32][33];
    const int k0 = blockIdx.x * 32, n0 = blockIdx.y * 32;
    const int c = threadIdx.x & 31, r8 = threadIdx.x >> 5;
#pragma unroll
    for (int rr = r8; rr < 32; rr += 8) {
        int k = k0 + rr, n = n0 + c;
        t[rr][c] = (k < K && n < N) ? W[(size_t)k * ldn + n] : 0.f;
    }
    __syncthreads();
#pragma unroll
    for (int rr = r8; rr < 32; rr += 8)
        Wt[(size_t)(n0 + rr) * Kpad + k0 + c] = __float2bfloat16(t[c][rr]);
}

// ---------------- precompute parity-effective 2x2 kernels: wg[ic*OC+oc][s*4+j] -----------------------
__global__ void k_weff(const float* __restrict__ w, float* __restrict__ wg, int IC, int OC)
{
    const int idx = blockIdx.x * 256 + threadIdx.x;
    if (idx >= IC * OC) return;
    const float* wp = w + (size_t)idx * 9;
    float wl[9];
#pragma unroll
    for (int k = 0; k < 9; ++k) wl[k] = wp[k];
    const float rm_[2][2][3] = {{{0.f,1.f,1.f},{1.f,0.f,0.f}},
                                {{0.f,0.f,1.f},{1.f,1.f,0.f}}};
    float* o = wg + (size_t)idx * 16;
#pragma unroll
    for (int py = 0; py < 2; ++py)
#pragma unroll
    for (int px = 0; px < 2; ++px)
#pragma unroll
    for (int r = 0; r < 2; ++r)
#pragma unroll
    for (int c = 0; c < 2; ++c) {
        float s = 0.f;
#pragma unroll
        for (int ky = 0; ky < 3; ++ky)
#pragma unroll
        for (int kx = 0; kx < 3; ++kx)
            s += rm_[py][r][ky] * rm_[px][c][kx] * wl[ky * 3 + kx];
        o[(r * 2 + c) * 4 + (py * 2 + px)] = s;     // transposed: [src][j]
    }
}

// ---------------- Bt4[s][n=oc*4+j][ic(pad32)] bf16 from weff (stage-4 MFMA B matrix) -----------------
__global__ void k_weffB(const float* __restrict__ weff, __hip_bfloat16* __restrict__ Bt4)
{
    const int t = blockIdx.x * 256 + threadIdx.x;   // t = s*128 + n
    if (t >= 512) return;
    const int s = t >> 7, n = t & 127;
    const int oc = n >> 2, j = n & 3;
    ushort* dst = (ushort*)Bt4 + (size_t)t * 32;
#pragma unroll
    for (int icb = 0; icb < 4; ++icb) {
        short8 pk;
#pragma unroll
        for (int u = 0; u < 8; ++u) {
            const int ic = icb * 8 + u;
            const float v = (ic < 25 && oc < 25) ? weff[((size_t)ic * 25 + oc) * 16 + s * 4 + j] : 0.f;
            pk[u] = f2bf_s(v);
        }
        *(short8*)(dst + icb * 8) = pk;
    }
}

// ---------------- border zero (border cells ONLY) -----------------------------------------------------
__global__ void k_zero_border(float* __restrict__ buf, int PH, int PW, int IR0, int IR1, int IC0, int IC1)
{
    float* plane = buf + (size_t)blockIdx.x * PH * PW;
    const int tid = threadIdx.x;
    const int topN = IR0 * PW;
    for (int i = tid; i < topN; i += 256) plane[i] = 0.f;
    const int botBase = IR1 * PW, botN = (PH - IR1) * PW;
    for (int i = tid; i < botN; i += 256) plane[botBase + i] = 0.f;
    const int rows = IR1 - IR0;
    const int wL = IC0, wR = PW - IC1, wLR = wL + wR;
    const int n = rows * wLR;
    for (int i = tid; i < n; i += 256) {
        const int r = i / wLR, c = i - r * wLR;
        const int col = (c < wL) ? c : (IC1 + c - wL);
        plane[(IR0 + r) * PW + col] = 0.f;
    }
}

// ---------------- d3p [64][25][130][66] f32 -> nhwc [64][130][66][32] bf16 (ch-pad 32) ----------------
__global__ void k_nhwc(const float* __restrict__ src, __hip_bfloat16* __restrict__ dst)
{
    const int idx = blockIdx.x * 256 + threadIdx.x;       // (b, p, q); 64*130*66 = 549120 exactly
    const int b = idx / 8580;
    const int rem = idx - b * 8580;
    const int p = rem / 66, q = rem - (rem / 66) * 66;
    const float* sp = src + ((size_t)b * 25 * 130 + p) * 66 + q;
    ushort* dp = (ushort*)dst + (size_t)idx * 32;
#pragma unroll
    for (int icb = 0; icb < 4; ++icb) {
        short8 pk;
#pragma unroll
        for (int u = 0; u < 8; ++u) {
            const int ic = icb * 8 + u;
            const float v = (ic < 25) ? sp[(size_t)ic * 130 * 66] : 0.f;
            pk[u] = f2bf_s(v);
        }
        *(short8*)(dp + icb * 8) = pk;
    }
}

// ---------------- rv = relu(rela_feats @ w_rela + b_rela) -> bf16 [32768][1024] ----------------------
__global__ void k_rv(const float* __restrict__ rela_feats, const float* __restrict__ w_rela,
                     const float* __restrict__ b_rela, __hip_bfloat16* __restrict__ rv)
{
    const int tid = threadIdx.x;
    const int r0 = blockIdx.x * 16;
    __shared__ float rf[16][8];
    if (tid < 128) rf[tid >> 3][tid & 7] = rela_feats[(size_t)(r0 + (tid >> 3)) * 8 + (tid & 7)];
    __syncthreads();
    const int row = r0 + (tid >> 4);
    const int cg = (tid & 15) * 64;
    float rloc[8];
#pragma unroll
    for (int f = 0; f < 8; ++f) rloc[f] = rf[tid >> 4][f];
    __hip_bfloat16* orow = rv + (size_t)row * 1024;
#pragma unroll
    for (int ch = 0; ch < 8; ++ch) {
        const int c = cg + ch * 8;
        float a[8];
        if (c < RNN_) {
            const float4 b0 = *(const float4*)(b_rela + c);
            const float4 b1 = *(const float4*)(b_rela + c + 4);
            a[0] = b0.x; a[1] = b0.y; a[2] = b0.z; a[3] = b0.w;
            a[4] = b1.x; a[5] = b1.y; a[6] = b1.z; a[7] = b1.w;
#pragma unroll
            for (int f = 0; f < 8; ++f) {
                const float4 w0 = *(const float4*)(w_rela + f * RNN_ + c);
                const float4 w1 = *(const float4*)(w_rela + f * RNN_ + c + 4);
                const float rfv = rloc[f];
                a[0] += rfv * w0.x; a[1] += rfv * w0.y; a[2] += rfv * w0.z; a[3] += rfv * w0.w;
                a[4] += rfv * w1.x; a[5] += rfv * w1.y; a[6] += rfv * w1.z; a[7] += rfv * w1.w;
            }
#pragma unroll
            for (int j = 0; j < 8; ++j) a[j] = fmaxf(a[j], 0.f);
        } else {
#pragma unroll
            for (int j = 0; j < 8; ++j) a[j] = 0.f;
        }
        short8 pk;
#pragma unroll
        for (int j = 0; j < 8; ++j) pk[j] = f2bf_s(a[j]);
        *(short8*)(orow + c) = pk;
    }
}

// ---------------- MFMA bf16 GEMM: C = A[M][Kpad] @ Bt[Npad][Kpad]^T, 128x128 tile, BK=64 --------------
template<int MODE>
__global__ __launch_bounds__(256)
void mfma_gemm(const __hip_bfloat16* __restrict__ A, const __hip_bfloat16* __restrict__ Bt, int Kpad,
               const float* __restrict__ bias, int ldc, int ncols,
               __hip_bfloat16* __restrict__ outB,
               const __half* __restrict__ P13H, const int* __restrict__ edges,
               const float* __restrict__ masks, int lgNT)
{
    __shared__ __align__(16) ushort smem[16384];    // 32 KB: lA0|lA1|lB0|lB1 (4x8KB) | ftile overlay
    ushort* lA0 = smem;
    ushort* lA1 = smem + 4096;
    ushort* lB0 = smem + 8192;
    ushort* lB1 = smem + 12288;
    const int tid = threadIdx.x;
    const int l = (blockIdx.x & 7) * ((int)gridDim.x >> 3) + ((int)blockIdx.x >> 3);
    const int n0 = (l & ((1 << lgNT) - 1)) * 128;
    const int m0 = (l >> lgNT) * 128;
    const int wave = tid >> 6, lane = tid & 63;
    const int wr = wave >> 1, wc = wave & 1;
    const int lr = lane >> 4, lc = lane & 15;
    const int lrow = lane >> 2;          // 0..15: row within wave's 16-row chunk
    const int lcol = (lane & 3) * 8;     // ushort offset of 16B chunk
    f32x4 acc[4][4];
#pragma unroll
    for (int i = 0; i < 4; ++i)
#pragma unroll
        for (int j = 0; j < 4; ++j) acc[i][j] = (f32x4){0.f, 0.f, 0.f, 0.f};

    for (int k0 = 0; k0 < Kpad; k0 += 64) {
        __syncthreads();                 // previous iter's ds_reads done before overwrite
#pragma unroll
        for (int j = 0; j < 2; ++j) {
            const int rbase = j * 64 + wave * 16;
            GLOAD_LDS16(A  + (size_t)(m0 + rbase + lrow) * Kpad + k0 + lcol,      &lA0[rbase * 32]);
            GLOAD_LDS16(A  + (size_t)(m0 + rbase + lrow) * Kpad + k0 + 32 + lcol, &lA1[rbase * 32]);
            GLOAD_LDS16(Bt + (size_t)(n0 + rbase + lrow) * Kpad + k0 + lcol,      &lB0[rbase * 32]);
            GLOAD_LDS16(Bt + (size_t)(n0 + rbase + lrow) * Kpad + k0 + 32 + lcol, &lB1[rbase * 32]);
        }
        __syncthreads();                 // drains vmcnt: both halves ready
#pragma unroll
        for (int h = 0; h < 2; ++h) {
            const ushort* hA = h ? lA1 : lA0;
            const ushort* hB = h ? lB1 : lB0;
            short8 af[4], bfr[4];
#pragma unroll
            for (int mi = 0; mi < 4; ++mi)
                af[mi] = *(const short8*)&hA[(wr * 64 + mi * 16 + lc) * 32 + lr * 8];
#pragma unroll
            for (int ni = 0; ni < 4; ++ni)
                bfr[ni] = *(const short8*)&hB[(wc * 64 + ni * 16 + lc) * 32 + lr * 8];
#pragma unroll
            for (int mi = 0; mi < 4; ++mi)
#pragma unroll
                for (int ni = 0; ni < 4; ++ni)
                    acc[mi][ni] = __builtin_amdgcn_mfma_f32_16x16x32_bf16(af[mi], bfr[ni], acc[mi][ni], 0, 0, 0);
        }
    }

    // ---------------- LDS-remap epilogue ----------------
    float* ftile = (float*)smem;         // [32][136] f32 (17408 B <= 32 KB)
    const int erow = tid >> 3;           // 0..31
    const int ecol0 = (tid & 7) * 16;    // 0..112
#pragma unroll
    for (int mi = 0; mi < 4; ++mi) {
        __syncthreads();                 // protect prior phase reads
#pragma unroll
        for (int ni = 0; ni < 4; ++ni) {
            const int colL = wc * 64 + ni * 16 + lc;
#pragma unroll
            for (int r = 0; r < 4; ++r)
                ftile[(wr * 16 + lr * 4 + r) * 136 + colL] = acc[mi][ni][r];
        }
        __syncthreads();
        const int rowL = (erow < 16) ? (mi * 16 + erow) : (64 + mi * 16 + (erow - 16));
        const int grow = m0 + rowL;
        const int gcol = n0 + ecol0;
        float v[16];
#pragma unroll
        for (int j = 0; j < 4; ++j) {
            const f32x4 t4 = *(const f32x4*)&ftile[erow * 136 + ecol0 + j * 4];
            v[j*4+0] = t4[0]; v[j*4+1] = t4[1]; v[j*4+2] = t4[2]; v[j*4+3] = t4[3];
        }
        if (MODE == 0) {
            short8 pk0, pk1;
#pragma unroll
            for (int j = 0; j < 16; ++j) {
                const int c = gcol + j;
                const float bb = (c < ncols) ? bias[c] : 0.f;
                const short s = f2bf_s(fmaxf(v[j] + bb, 0.f));
                if (j < 8) pk0[j] = s; else pk1[j - 8] = s;
            }
            *(short8*)(outB + (size_t)grow * 1024 + gcol)     = pk0;
            *(short8*)(outB + (size_t)grow * 1024 + gcol + 8) = pk1;
        } else if (MODE == 1) {
            __half* outH = (__half*)outB;
            if (gcol + 15 < ncols) {
                __half h[16];
#pragma unroll
                for (int j = 0; j < 16; ++j) h[j] = __float2half(v[j]);
                *(short8*)(outH + (size_t)grow * ldc + gcol)     = *(short8*)&h[0];
                *(short8*)(outH + (size_t)grow * ldc + gcol + 8) = *(short8*)&h[8];
            } else {
#pragma unroll
                for (int j = 0; j < 16; ++j) {
                    const int c = gcol + j;
                    if (c < ncols) outH[(size_t)grow * ldc + c] = __float2half(v[j]);
                }
            }
        } else {
            const int b = grow >> 9;           // NR = 512
            const int e0 = edges[grow * 2], e1 = edges[grow * 2 + 1];
            const float mk = masks[grow];
            const __half* p0 = P13H + (size_t)(b * NO_ + e0) * 2048 + gcol;
            const __half* p1 = P13H + (size_t)(b * NO_ + e1) * 2048 + 1024 + gcol;
            if (gcol + 15 < ncols) {
                __half h0[16], h1[16];
                *(short8*)&h0[0] = *(const short8*)p0;  *(short8*)&h0[8] = *(const short8*)(p0 + 8);
                *(short8*)&h1[0] = *(const short8*)p1;  *(short8*)&h1[8] = *(const short8*)(p1 + 8);
                float bb[16];
#pragma unroll
                for (int j = 0; j < 4; ++j) {
                    const float4 b4 = *(const float4*)(bias + gcol + j * 4);
                    bb[j*4+0] = b4.x; bb[j*4+1] = b4.y; bb[j*4+2] = b4.z; bb[j*4+3] = b4.w;
                }
                short8 pk0, pk1;
#pragma unroll
                for (int j = 0; j < 16; ++j) {
                    float val = v[j] + bb[j] + __half2float(h0[j]) + __half2float(h1[j]);
                    const short s = f2bf_s(fmaxf(val, 0.f) * mk);
                    if (j < 8) pk0[j] = s; else pk1[j - 8] = s;
                }
                *(short8*)(outB + (size_t)grow * RNN_ + gcol)     = pk0;
                *(short8*)(outB + (size_t)grow * RNN_ + gcol + 8) = pk1;
            } else if (gcol < ncols) {
#pragma unroll
                for (int j = 0; j < 16; ++j) {
                    const int c = gcol + j;
                    if (c < ncols) {
                        float val = v[j] + bias[c] + __half2float(p0[j]) + __half2float(p1[j]);
                        outB[(size_t)grow * RNN_ + c] = __float2bfloat16(fmaxf(val, 0.f) * mk);
                    }
                }
            }
        }
    }
}

// ---------------- stage-4 ConvT as MFMA GEMM over NHWC bf16 -------------------------------------------
// C[row=(b,a,g)][n=oc*4+j] = sum_s sum_ic nhwc[b][a+sr][g+1+sc][ic] * Bt4[s][n][ic]
// M = 64*128*64 (a,g padded; garbage rows read zero borders, filtered at store). K = 4 shifts x 32 ic.
// A staged to LDS via global_load_lds (4x8KB, one barrier pair); B fragments read direct from global
// (32 KB, L1-resident after first block). Epilogue: ftile remap + bias + sigmoid + NCHW float2 stores.
__global__ __launch_bounds__(256)
void mfma_conv4(const __hip_bfloat16* __restrict__ nhwc, const __hip_bfloat16* __restrict__ Bt4,
                const float* __restrict__ bias, float* __restrict__ xout)
{
    __shared__ __align__(16) ushort smem[16384];    // 32 KB: A[4][128][32] | ftile overlay
    const int tid = threadIdx.x;
    const int m0 = (int)blockIdx.x * 128;
    const int wave = tid >> 6, lane = tid & 63;
    const int wr = wave >> 1, wc = wave & 1;
    const int lr = lane >> 4, lc = lane & 15;
    const int lrow = lane >> 2;
    const int lcol = (lane & 3) * 8;
    f32x4 acc[4][4];
#pragma unroll
    for (int i = 0; i < 4; ++i)
#pragma unroll
        for (int j = 0; j < 4; ++j) acc[i][j] = (f32x4){0.f, 0.f, 0.f, 0.f};

#pragma unroll
    for (int s = 0; s < 4; ++s) {
        const int sr = s >> 1, sc = s & 1;
#pragma unroll
        for (int j = 0; j < 2; ++j) {
            const int rbase = j * 64 + wave * 16;
            const int row = m0 + rbase + lrow;
            const int b = row >> 13, a = (row >> 6) & 127, g = row & 63;
            GLOAD_LDS16(nhwc + ((size_t)(b * 130 + a + sr) * 66 + (g + 1 + sc)) * 32 + lcol,
                        &smem[s * 4096 + rbase * 32]);
        }
    }
    __syncthreads();                     // drains vmcnt: all 4 shift-tiles ready
#pragma unroll
    for (int s = 0; s < 4; ++s) {
        const ushort* lA = &smem[s * 4096];
        short8 af[4], bfr[4];
#pragma unroll
        for (int mi = 0; mi < 4; ++mi)
            af[mi] = *(const short8*)&lA[(wr * 64 + mi * 16 + lc) * 32 + lr * 8];
#pragma unroll
        for (int ni = 0; ni < 4; ++ni)
            bfr[ni] = *(const short8*)((const ushort*)Bt4 +
                      ((size_t)(s * 128 + wc * 64 + ni * 16 + lc)) * 32 + lr * 8);
#pragma unroll
        for (int mi = 0; mi < 4; ++mi)
#pragma unroll
            for (int ni = 0; ni < 4; ++ni)
                acc[mi][ni] = __builtin_amdgcn_mfma_f32_16x16x32_bf16(af[mi], bfr[ni], acc[mi][ni], 0, 0, 0);
    }

    // ---------------- epilogue: remap + sigmoid + NCHW store ----------------
    float* ftile = (float*)smem;         // [32][136] f32
    const int erow = tid >> 3;
    const int ecol0 = (tid & 7) * 16;    // 16 cols = 4 oc x 4 j
#pragma unroll
    for (int mi = 0; mi < 4; ++mi) {
        __syncthreads();
#pragma unroll
        for (int ni = 0; ni < 4; ++ni) {
            const int colL = wc * 64 + ni * 16 + lc;
#pragma unroll
            for (int r = 0; r < 4; ++r)
                ftile[(wr * 16 + lr * 4 + r) * 136 + colL] = acc[mi][ni][r];
        }
        __syncthreads();
        const int rowL = (erow < 16) ? (mi * 16 + erow) : (64 + mi * 16 + (erow - 16));
        const int grow = m0 + rowL;
        const int b = grow >> 13, a = (grow >> 6) & 127, g = grow & 63;
        float v[16];
#pragma unroll
        for (int j = 0; j < 4; ++j) {
            const f32x4 t4 = *(const f32x4*)&ftile[erow * 136 + ecol0 + j * 4];
            v[j*4+0] = t4[0]; v[j*4+1] = t4[1]; v[j*4+2] = t4[2]; v[j*4+3] = t4[3];
        }
        if (a < 127 && g < 63) {
#pragma unroll
            for (int k = 0; k < 4; ++k) {
                const int oc = (ecol0 >> 2) + k;
                if (oc < 25) {
                    const float bv = bias[oc];
                    const float j0 = 1.f / (1.f + expf(-(v[k*4+0] + bv)));
                    const float j1 = 1.f / (1.f + expf(-(v[k*4+1] + bv)));
                    const float j2 = 1.f / (1.f + expf(-(v[k*4+2] + bv)));
                    const float j3 = 1.f / (1.f + expf(-(v[k*4+3] + bv)));
                    float* dp = xout + ((size_t)(b * 25 + oc) * 254 + 2 * a) * 126 + 2 * g;
                    *reinterpret_cast<float2*>(dp)       = make_float2(j0, j1);
                    *reinterpret_cast<float2*>(dp + 126) = make_float2(j2, j3);
                }
            }
        }
    }
}

// ---------------- split-K skinny GEMM (M=64): part[kz][64][N] = A[64][kz-chunk] @ W[chunk][N] ---------
__global__ void k_gemm_sk(const float* __restrict__ A, const float* __restrict__ W,
                          float* __restrict__ part, int N, int K, int ldw, int Kc)
{
    __shared__ float As[16][68];
    __shared__ float Ws[16][68];
    const int tid = threadIdx.x;
    const int n0 = blockIdx.x * 64;
    const int kz = blockIdx.y;
    const int kstart = kz * Kc;
    const int kend = (kstart + Kc < K) ? (kstart + Kc) : K;
    const int ty = tid >> 4, tx = tid & 15;
    float acc[4][4] = {};
    for (int k0 = kstart; k0 < kend; k0 += 16) {
#pragma unroll
        for (int i = 0; i < 4; ++i) {
            int lin = i * 256 + tid;
            int r = lin >> 4, kk = lin & 15;
            int k = k0 + kk;
            As[kk][r] = (k < kend) ? A[(size_t)r * K + k] : 0.f;
            int kr = lin >> 6, c = lin & 63;
            int kw = k0 + kr, cc = n0 + c;
            Ws[kr][c] = (kw < kend && cc < N) ? W[(size_t)kw * ldw + cc] : 0.f;
        }
        __syncthreads();
#pragma unroll
        for (int kk = 0; kk < 16; ++kk) {
            const float4 av = *reinterpret_cast<const float4*>(&As[kk][ty * 4]);
            const float4 wv = *reinterpret_cast<const float4*>(&Ws[kk][tx * 4]);
            const float a4[4] = {av.x, av.y, av.z, av.w};
            const float w4[4] = {wv.x, wv.y, wv.z, wv.w};
#pragma unroll
            for (int i = 0; i < 4; ++i)
#pragma unroll
                for (int j = 0; j < 4; ++j) acc[i][j] += a4[i] * w4[j];
        }
        __syncthreads();
    }
#pragma unroll
    for (int i = 0; i < 4; ++i) {
        const int row = ty * 4 + i;
#pragma unroll
        for (int j = 0; j < 4; ++j) {
            const int col = n0 + tx * 4 + j;
            if (col < N)
                part[((size_t)kz * 64 + row) * N + col] = acc[i][j];
        }
    }
}

// ---------------- reduce split-K partials + bias + act -------------------------------------------------
__global__ void k_sk_reduce(const float* __restrict__ part, const float* __restrict__ bias,
                            float* __restrict__ out, int N, int KS, int ldo, int act)
{
    const int idx = blockIdx.x * 256 + threadIdx.x;
    if (idx >= 64 * N) return;
    const int row = idx / N, col = idx - row * N;
    float s = bias[col];
    for (int z = 0; z < KS; ++z) s += part[((size_t)z * 64 + row) * N + col];
    if (act) s = fmaxf(s, 0.f);
    out[(size_t)row * ldo + col] = s;
}

// ---------------- attention dot: dot[row] = tanh(feats[row,:]) . w_att + b (vectorized bf16) ----------
__global__ void k_att_dot(const __hip_bfloat16* __restrict__ feats, const float* __restrict__ w_att,
                          const float* __restrict__ b_att, float* __restrict__ dot, int D, int ld)
{
    const int row = blockIdx.x;
    const int tid = threadIdx.x;   // 256
    const int c = tid * 4;
    float s = 0.f;
    if (c < D) {
        const ushort4 v = *(const ushort4*)(feats + (size_t)row * ld + c);
        const float4 wv = *(const float4*)(w_att + c);
        s  = tanhf(bf2f(v.x)) * wv.x;
        s += tanhf(bf2f(v.y)) * wv.y;
        s += tanhf(bf2f(v.z)) * wv.z;
        s += tanhf(bf2f(v.w)) * wv.w;
    }
#pragma unroll
    for (int o = 32; o > 0; o >>= 1) s += __shfl_down(s, o, 64);
    __shared__ float part[4];
    if ((tid & 63) == 0) part[tid >> 6] = s;
    __syncthreads();
    if (tid == 0) dot[row] = part[0] + part[1] + part[2] + part[3] + b_att[0];
}

// ---------------- masked, renormalized softmax weights (block per batch, blockDim == Nn) -------------
__global__ void k_softmax(const float* __restrict__ dot, const float* __restrict__ mask,
                          float* __restrict__ wgt, int Nn)
{
    const int b = blockIdx.x, tid = threadIdx.x;
    __shared__ float red[512];
    float v = dot[b * Nn + tid];
    red[tid] = v; __syncthreads();
    for (int s = Nn >> 1; s > 0; s >>= 1) { if (tid < s) red[tid] = fmaxf(red[tid], red[tid + s]); __syncthreads(); }
    float mx = red[0]; __syncthreads();
    float e = expf(v - mx);
    red[tid] = e; __syncthreads();
    for (int s = Nn >> 1; s > 0; s >>= 1) { if (tid < s) red[tid] += red[tid + s]; __syncthreads(); }
    float sm = red[0]; __syncthreads();
    float w0 = (e / sm) * mask[b * Nn + tid];
    red[tid] = w0; __syncthreads();
    for (int s = Nn >> 1; s > 0; s >>= 1) { if (tid < s) red[tid] += red[tid + s]; __syncthreads(); }
    wgt[b * Nn + tid] = w0 / red[0];
}

// ---------------- weighted sum: out[b, off+d0..3] = sum_n wgt[b,n]*feats[b,n,d] (vectorized) ----------
__global__ void k_wsum(const __hip_bfloat16* __restrict__ feats, const float* __restrict__ wgt,
                       float* __restrict__ out, int Nn, int D, int ld, int ldo, int off)
{
    const int b = blockIdx.x;
    const int tid = threadIdx.x;     // 256
    __shared__ float wl[512];
    for (int i = tid; i < Nn; i += 256) wl[i] = wgt[b * Nn + i];
    __syncthreads();
    const int d0 = tid * 4;
    if (d0 >= D) return;
    float a0 = 0.f, a1 = 0.f, a2 = 0.f, a3 = 0.f;
    const __hip_bfloat16* fp = feats + (size_t)b * Nn * ld + d0;
#pragma unroll 8
    for (int n = 0; n < Nn; ++n) {
        const ushort4 v = *(const ushort4*)(fp + (size_t)n * ld);
        const float w = wl[n];
        a0 += w * bf2f(v.x); a1 += w * bf2f(v.y);
        a2 += w * bf2f(v.z); a3 += w * bf2f(v.w);
    }
    *(float4*)(out + (size_t)b * ldo + off + d0) = make_float4(a0, a1, a2, a3);
}

// ---------------- parity up2+ConvT: 1 quad/thread, 5 oc/thread, PACKED f32, SGPR weights --------------
__global__ void k_convt5(const float* __restrict__ src, const float* __restrict__ wg,
                         const float* __restrict__ bias, float* __restrict__ dst,
                         int IC, int OC, int SH, int SW, int act,
                         int dro, int dco, int DPH, int DPW)
{
    const int QH = SH + 1, QW = SW + 1;
    const int ocg = blockIdx.y, b = blockIdx.z;
    const int tid = threadIdx.x;
    const int p = blockIdx.x * blockDim.x + tid;
    if (p >= QH * QW) return;
    const int a = p / QW, g = p % QW;
    const bool rm = (a > 0), rp = (a < SH);
    const bool cm = (g > 0), cp = (g < SW);
    f32x2v acc2[5][2];
#pragma unroll
    for (int ol = 0; ol < 5; ++ol) { acc2[ol][0] = (f32x2v){0.f, 0.f}; acc2[ol][1] = (f32x2v){0.f, 0.f}; }
    const float* sb = src + (size_t)(b * IC) * SH * SW;
    const int base = (a - 1) * SW + (g - 1);
    for (int ic = 0; ic < IC; ++ic) {
        const float* s = sb + (size_t)ic * SH * SW;
        const float s00 = (rm && cm) ? s[base] : 0.f;
        const float s01 = (rm && cp) ? s[base + 1] : 0.f;
        const float s10 = (rp && cm) ? s[base + SW] : 0.f;
        const float s11 = (rp && cp) ? s[base + SW + 1] : 0.f;
        const f32x2v b0 = {s00, s00}, b1 = {s01, s01}, b2 = {s10, s10}, b3 = {s11, s11};
        const float* wf = wg + ((size_t)ic * OC + ocg * 5) * 16;   // wave-uniform
#pragma unroll
        for (int ol = 0; ol < 5; ++ol) {
            const f32x4v w0 = *(const f32x4v*)(wf + ol * 16 + 0);
            const f32x4v w1 = *(const f32x4v*)(wf + ol * 16 + 4);
            const f32x4v w2 = *(const f32x4v*)(wf + ol * 16 + 8);
            const f32x4v w3 = *(const f32x4v*)(wf + ol * 16 + 12);
            acc2[ol][0] += b0 * __builtin_shufflevector(w0, w0, 0, 1);
            acc2[ol][0] += b1 * __builtin_shufflevector(w1, w1, 0, 1);
            acc2[ol][0] += b2 * __builtin_shufflevector(w2, w2, 0, 1);
            acc2[ol][0] += b3 * __builtin_shufflevector(w3, w3, 0, 1);
            acc2[ol][1] += b0 * __builtin_shufflevector(w0, w0, 2, 3);
            acc2[ol][1] += b1 * __builtin_shufflevector(w1, w1, 2, 3);
            acc2[ol][1] += b2 * __builtin_shufflevector(w2, w2, 2, 3);
            acc2[ol][1] += b3 * __builtin_shufflevector(w3, w3, 2, 3);
        }
    }
#pragma unroll
    for (int ol = 0; ol < 5; ++ol) {
        const int oc = ocg * 5 + ol;
        const float bv = bias[oc];
        float a00 = acc2[ol][0].x + bv, a01 = acc2[ol][0].y + bv;
        float a10 = acc2[ol][1].x + bv, a11 = acc2[ol][1].y + bv;
        if (act == 1) {
            a00 = fmaxf(a00, 0.f); a01 = fmaxf(a01, 0.f);
            a10 = fmaxf(a10, 0.f); a11 = fmaxf(a11, 0.f);
        } else {
            a00 = 1.f / (1.f + expf(-a00)); a01 = 1.f / (1.f + expf(-a01));
            a10 = 1.f / (1.f + expf(-a10)); a11 = 1.f / (1.f + expf(-a11));
        }
        float* dp = dst + ((size_t)(b * OC + oc) * DPH + 2 * a + dro) * DPW + 2 * g + dco;
        *reinterpret_cast<float2*>(dp)       = make_float2(a00, a01);
        *reinterpret_cast<float2*>(dp + DPW) = make_float2(a10, a11);
    }
}

// ---------------- parity up2+ConvT: 2 VERTICAL quads x 5 oc, SCALAR FMA, SGPR weights -----------------
// NO-BOUNDS variant (padded src). Stage 3 only (stage 4 is mfma_conv4 now).
__global__ void k_convtv(const float* __restrict__ src, int SPP, int SPW,
                         const float* __restrict__ wg,
                         const float* __restrict__ bias, float* __restrict__ dst,
                         int IC, int OC, int QH, int QW, int act, int LG,
                         int dro, int dco, int DPH, int DPW)
{
    const int ocg = blockIdx.y, b = blockIdx.z;
    const int tid = threadIdx.x;
    const int g = tid & ((1 << LG) - 1);
    const int a0 = blockIdx.x * ((256 >> LG) * 2) + (tid >> LG) * 2;
    if (g >= QW || a0 >= QH) return;
    float acc[5][2][4];
#pragma unroll
    for (int ol = 0; ol < 5; ++ol)
#pragma unroll
        for (int q = 0; q < 2; ++q)
#pragma unroll
            for (int j = 0; j < 4; ++j) acc[ol][q][j] = 0.f;
    const float* sb = src + (size_t)(b * IC) * SPP;
    const int rbase = a0 * SPW + g + 1;
    for (int ic = 0; ic < IC; ++ic) {
        const float* s = sb + (size_t)ic * SPP;
        float sv[3][2];
#pragma unroll
        for (int i = 0; i < 3; ++i) {
            sv[i][0] = s[rbase + i * SPW];
            sv[i][1] = s[rbase + i * SPW + 1];
        }
        const float* wf = wg + ((size_t)ic * OC + ocg * 5) * 16;   // wave-uniform (SGPR operands)
#pragma unroll
        for (int ol = 0; ol < 5; ++ol) {
#pragma unroll
            for (int q = 0; q < 2; ++q) {
#pragma unroll
                for (int j = 0; j < 4; ++j) {
                    acc[ol][q][j] += sv[q][0]     * wf[ol * 16 +  0 + j];
                    acc[ol][q][j] += sv[q][1]     * wf[ol * 16 +  4 + j];
                    acc[ol][q][j] += sv[q + 1][0] * wf[ol * 16 +  8 + j];
                    acc[ol][q][j] += sv[q + 1][1] * wf[ol * 16 + 12 + j];
                }
            }
        }
    }
    const bool q1ok = (a0 + 1 < QH);
#pragma unroll
    for (int ol = 0; ol < 5; ++ol) {
        const int oc = ocg * 5 + ol;
        const float bv = bias[oc];
        float* dp0 = dst + ((size_t)(b * OC + oc) * DPH + 2 * a0 + dro) * DPW + 2 * g + dco;
#pragma unroll
        for (int q = 0; q < 2; ++q) {
            if (q == 1 && !q1ok) continue;
            float v0 = acc[ol][q][0] + bv, v1 = acc[ol][q][1] + bv;
            float v2 = acc[ol][q][2] + bv, v3 = acc[ol][q][3] + bv;
            if (act == 1) {
                v0 = fmaxf(v0, 0.f); v1 = fmaxf(v1, 0.f);
                v2 = fmaxf(v2, 0.f); v3 = fmaxf(v3, 0.f);
            } else {
                v0 = 1.f / (1.f + expf(-v0)); v1 = 1.f / (1.f + expf(-v1));
                v2 = 1.f / (1.f + expf(-v2)); v3 = 1.f / (1.f + expf(-v3));
            }
            float* dp = dp0 + q * 2 * DPW;
            *reinterpret_cast<float2*>(dp)       = make_float2(v0, v1);
            *reinterpret_cast<float2*>(dp + DPW) = make_float2(v2, v3);
        }
    }
}

extern "C" void kernel_launch(void* const* d_in, const int* in_sizes, int n_in,
                              void* d_out, int out_size, void* d_ws, size_t ws_size,
                              hipStream_t stream)
{
    const int*   obj_labels = (const int*)  d_in[0];
    const float* obj_masks  = (const float*)d_in[1];
    const float* rela_masks = (const float*)d_in[2];
    const int*   rela_edges = (const int*)  d_in[3];
    const float* rela_feats = (const float*)d_in[4];
    const float* box_feats  = (const float*)d_in[5];
    const float* emb_table  = (const float*)d_in[6];
    const float* w_objfeat  = (const float*)d_in[7];
    const float* b_objfeat  = (const float*)d_in[8];
    const float* w_cat      = (const float*)d_in[9];
    const float* b_cat      = (const float*)d_in[10];
    const float* w_obj      = (const float*)d_in[11];
    const float* b_obj      = (const float*)d_in[12];
    const float* w_rela     = (const float*)d_in[13];
    const float* b_rela     = (const float*)d_in[14];
    const float* w_gnn      = (const float*)d_in[15];
    const float* b_gnn      = (const float*)d_in[16];
    const float* w_att_obj  = (const float*)d_in[17];
    const float* b_att_obj  = (const float*)d_in[18];
    const float* w_att_rela = (const float*)d_in[19];
    const float* b_att_rela = (const float*)d_in[20];
    const float* w_read     = (const float*)d_in[21];
    const float* b_read     = (const float*)d_in[22];
    const float* w_fc       = (const float*)d_in[23];
    const float* b_fc       = (const float*)d_in[24];
    const float* wt1 = (const float*)d_in[25]; const float* bt1 = (const float*)d_in[26];
    const float* wt2 = (const float*)d_in[27]; const float* bt2 = (const float*)d_in[28];
    const float* wt3 = (const float*)d_in[29]; const float* bt3 = (const float*)d_in[30];
    const float* wt4 = (const float*)d_in[31]; const float* bt4 = (const float*)d_in[32];

    float* ws = (float*)d_ws;
    // layout (float units)
    __hip_bfloat16* objembB  = (__hip_bfloat16*)(ws);                  // [0, 524288)
    __hip_bfloat16* obj_vecsB= (__hip_bfloat16*)(ws + 524288);         // [524288, 4718592)
    __hip_bfloat16* w_objT   = (__hip_bfloat16*)(ws + 4718592);        // [4718592, 4784128)
    __hip_bfloat16* w1T      = (__hip_bfloat16*)(ws + 4784128);        // [4784128, 5308416)
    __hip_bfloat16* w3T      = (__hip_bfloat16*)(ws + 5308416);        // [5308416, 5832704)  (adjacent!)
    __hip_bfloat16* w2T      = (__hip_bfloat16*)(ws + 5832704);        // [5832704, 6356992)
    __half*         P13H     = (__half*)(ws + 6356992);                // 8192*2048 f16 = [6356992, 14745600)
    __hip_bfloat16* rvB      = (__hip_bfloat16*)(ws + 14745600);       // [14745600, 31522816)
    __hip_bfloat16* newRB    = (__hip_bfloat16*)(ws + 31522816);       // [31522816, 47906816)
    float* dot_obj = ws + 47906816;
    float* dot_rel = dot_obj + 8192;
    float* wgt_obj = dot_rel + 32768;
    float* wgt_rel = wgt_obj + 8192;
    float* a_cat   = wgt_rel + 32768;                                  // 64*2000 = 128000
    float* part_enc = a_cat + 128000;                                  // 524288
    float* part_fc  = part_enc + 524288;                               // 1376256 -> end 50,017,184
    float* weff1 = ws + 50017184;                                      // 12800
    float* weff2 = weff1 + 12800;                                      // 10000
    float* weff3 = weff2 + 10000;
    float* weff4 = weff3 + 10000;                                      // end 50,059,984
    __hip_bfloat16* Bt4 = (__hip_bfloat16*)(ws + 50059984);            // 4*128*32 bf16 = 8192 f -> 50,068,176
    // decoder aliases (P13H/rvB/newRB dead after attention): d1 unpadded; d2p/d3p zero-PADDED planes
    float* d0  = ws;                   // objembB region, dead after GEMM1
    float* d1  = ws + 6356992;         // [64][25][30][14] = 672,000 f
    float* d2p = ws + 7028992;         // [64][25][66][34] -> ends 10,619,392
    float* d3p = ws + 10619392;        // [64][25][130][66] -> ends 24,347,392
    __hip_bfloat16* nhwc4 = (__hip_bfloat16*)(ws + 24347392);          // [64][130][66][32] bf16 = 8,785,920 f -> 33,133,312 (dead rvB/newRB)
    float* enc  = (float*)d_out;
    float* xout = (float*)d_out + 65536;

    // 0. weight transposes -> bf16; conv weff tables; stage-4 MFMA B matrix
    k_transpose<<<dim3(4, 32),  256, 0, stream>>>(w_obj, w_objT, 128, RNN_, RNN_, 128);
    k_transpose<<<dim3(32, 32), 256, 0, stream>>>(w_gnn,                      w1T, RNN_, RNN_, RNN_, 1024);
    k_transpose<<<dim3(32, 32), 256, 0, stream>>>(w_gnn + (size_t)2*RNN_*RNN_,w3T, RNN_, RNN_, RNN_, 1024);
    k_transpose<<<dim3(32, 32), 256, 0, stream>>>(w_gnn + (size_t)RNN_*RNN_,  w2T, RNN_, RNN_, RNN_, 1024);
    k_weff<<<dim3(4), 256, 0, stream>>>(wt1, weff1, 32, 25);
    k_weff<<<dim3(3), 256, 0, stream>>>(wt2, weff2, 25, 25);
    k_weff<<<dim3(3), 256, 0, stream>>>(wt3, weff3, 25, 25);
    k_weff<<<dim3(3), 256, 0, stream>>>(wt4, weff4, 25, 25);
    k_weffB<<<dim3(2), 256, 0, stream>>>(weff4, Bt4);
    // 1. object embeddings -> bf16
    k_obj_embed<<<dim3(8192), dim3(128), 0, stream>>>(obj_labels, box_feats, emb_table,
                                                      w_objfeat, b_objfeat, w_cat, b_cat, objembB);
    // 2. obj_vecs = relu(obj_embed @ w_obj + b) -> bf16 [8192][1024]   (lgNT=3)
    mfma_gemm<0><<<dim3(512), 256, 0, stream>>>(objembB, w_objT, 128, b_obj,
                                                0, RNN_, obj_vecsB, nullptr, nullptr, nullptr, 3);
    // 3. P13 = obj_vecs @ [W1 | W3] (merged, N=2048) -> f16 [8192][2048]  (lgNT=4)
    mfma_gemm<1><<<dim3(1024), 256, 0, stream>>>(obj_vecsB, w1T, 1024, nullptr,
                                                 2048, 2048, (__hip_bfloat16*)P13H, nullptr, nullptr, nullptr, 4);
    // 4. rv -> bf16 [32768][1024]
    k_rv<<<dim3(2048), 256, 0, stream>>>(rela_feats, w_rela, b_rela, rvB);
    // 5. GNN: new_rela = relu(rv @ W2 + b + f16 P13 gathers) * mask -> bf16 [32768][1000]  (lgNT=3)
    mfma_gemm<2><<<dim3(2048), 256, 0, stream>>>(rvB, w2T, 1024, b_gnn,
                                                 0, RNN_, newRB, P13H, rela_edges, rela_masks, 3);
    // 6. attention dots
    k_att_dot<<<8192,  256, 0, stream>>>(obj_vecsB, w_att_obj,  b_att_obj,  dot_obj, RNN_, 1024);
    k_att_dot<<<32768, 256, 0, stream>>>(newRB,     w_att_rela, b_att_rela, dot_rel, RNN_, RNN_);
    // 7. softmax weights
    k_softmax<<<64, 128, 0, stream>>>(dot_obj, obj_masks,  wgt_obj, 128);
    k_softmax<<<64, 512, 0, stream>>>(dot_rel, rela_masks, wgt_rel, 512);
    // 8. attention pooling -> a_cat (64 x 2000)
    k_wsum<<<dim3(64), 256, 0, stream>>>(obj_vecsB, wgt_obj, a_cat, 128, RNN_, 1024, 2000, 0);
    k_wsum<<<dim3(64), 256, 0, stream>>>(newRB,     wgt_rel, a_cat, 512, RNN_, RNN_, 2000, RNN_);
    // 9. enc = relu(a_cat @ w_read + b) -> d_out  (split-K)
    k_gemm_sk<<<dim3(16, 8), 256, 0, stream>>>(a_cat, w_read, part_enc, DIM_, 2000, DIM_, 256);
    k_sk_reduce<<<dim3(256), 256, 0, stream>>>(part_enc, b_read, enc, DIM_, 8, DIM_, 1);
    // 10. fc: d0 = enc @ w_fc + b_fc  (split-K)
    k_gemm_sk<<<dim3(42, 8), 256, 0, stream>>>(enc, w_fc, part_fc, 2688, DIM_, 2688, 128);
    k_sk_reduce<<<dim3(672), 256, 0, stream>>>(part_fc, b_fc, d0, 2688, 8, 2688, 0);
    // 11. decoder: stages 1-3 as before; stage 4 via NHWC repack + MFMA GEMM
    k_zero_border<<<dim3(1600), 256, 0, stream>>>(d2p, 66, 34, 1, 63, 2, 32);
    k_zero_border<<<dim3(1600), 256, 0, stream>>>(d3p, 130, 66, 1, 127, 2, 64);
    k_convt5<<<dim3(1, 5, 64), 256, 0, stream>>>(d0, weff1, bt1, d1, 32, 25, 14, 6, 1, 0, 0, 30, 14);
    k_convt5<<<dim3(2, 5, 64), 256, 0, stream>>>(d1, weff2, bt2, d2p, 25, 25, 30, 14, 1, 1, 2, 66, 34);
    k_convtv<<<dim3(4, 5, 64), 256, 0, stream>>>(d2p, 66 * 34, 34, weff3, bt3, d3p,
                                                 25, 25, 63, 31, 1, 5, 1, 2, 130, 66);
    k_nhwc<<<dim3(2145), 256, 0, stream>>>(d3p, nhwc4);
    mfma_conv4<<<dim3(4096), 256, 0, stream>>>(nhwc4, Bt4, bt4, xout);
}

// Round 27
// 658.933 us; speedup vs baseline: 1.1607x; 1.1607x over previous
//
#include <hip/hip_runtime.h>
#include <hip/hip_bf16.h>
#include <hip/hip_fp16.h>

#define B_    64
#define NO_   128
#define NR_   512
#define RNN_  1000
#define DIM_  1024

typedef short short8 __attribute__((ext_vector_type(8)));   // 8 bf16 (4 VGPRs)
typedef float f32x4  __attribute__((ext_vector_type(4)));
typedef float f32x2v __attribute__((ext_vector_type(2)));
typedef float f32x4v __attribute__((ext_vector_type(4)));

static __device__ __forceinline__ float bf2f(unsigned short u) {
    union { unsigned int i; float f; } x; x.i = ((unsigned int)u) << 16; return x.f;
}
static __device__ __forceinline__ short f2bf_s(float f) {
    __hip_bfloat16 h = __float2bfloat16(f);
    return *reinterpret_cast<short*>(&h);
}

#define GLOAD_LDS16(gp, lp) \
    __builtin_amdgcn_global_load_lds((const __attribute__((address_space(1))) void*)(gp), \
                                     (__attribute__((address_space(3))) void*)(lp), 16, 0, 0)

// ---------------- K1: obj_embed = relu(cat[relu(box@Wf+b), relu(emb[label])] @ Wcat + b) -> bf16 -------
__global__ void k_obj_embed(const int* __restrict__ labels,
                            const float* __restrict__ box_feats,
                            const float* __restrict__ emb_table,
                            const float* __restrict__ w_objfeat, const float* __restrict__ b_objfeat,
                            const float* __restrict__ w_cat, const float* __restrict__ b_cat,
                            __hip_bfloat16* __restrict__ out)
{
    const int row = blockIdx.x;      // b*NO + n
    const int tid = threadIdx.x;     // 0..127
    __shared__ __align__(16) float cat[256];
    __shared__ float bf[5];
    if (tid < 5) bf[tid] = box_feats[row * 5 + tid];
    __syncthreads();
    float acc = b_objfeat[tid];
#pragma unroll
    for (int k = 0; k < 5; ++k) acc += bf[k] * w_objfeat[k * 128 + tid];
    cat[tid] = fmaxf(acc, 0.f);
    const int label = labels[row];
    cat[128 + tid] = fmaxf(emb_table[label * 128 + tid], 0.f);
    __syncthreads();
    float acc2 = b_cat[tid];
#pragma unroll 4
    for (int k4 = 0; k4 < 64; ++k4) {
        const f32x4 c4 = *(const f32x4*)&cat[k4 * 4];
        acc2 += c4[0] * w_cat[(k4 * 4 + 0) * 128 + tid];
        acc2 += c4[1] * w_cat[(k4 * 4 + 1) * 128 + tid];
        acc2 += c4[2] * w_cat[(k4 * 4 + 2) * 128 + tid];
        acc2 += c4[3] * w_cat[(k4 * 4 + 3) * 128 + tid];
    }
    out[(size_t)row * 128 + tid] = __float2bfloat16(fmaxf(acc2, 0.f));
}

// ---------------- tiled transpose-convert: Wt[n][k] = bf16(W[k][n]), zero-padded to [Npad][Kpad] -------
__global__ void k_transpose(const float* __restrict__ W, __hip_bfloat16* __restrict__ Wt,
                            int K, int N, int ldn, int Kpad)
{
    __shared__ float t[32][33];
    const int k0 = blockIdx.x * 32, n0 = blockIdx.y * 32;
    const int c = threadIdx.x & 31, r8 = threadIdx.x >> 5;
#pragma unroll
    for (int rr = r8; rr < 32; rr += 8) {
        int k = k0 + rr, n = n0 + c;
        t[rr][c] = (k < K && n < N) ? W[(size_t)k * ldn + n] : 0.f;
    }
    __syncthreads();
#pragma unroll
    for (int rr = r8; rr < 32; rr += 8)
        Wt[(size_t)(n0 + rr) * Kpad + k0 + c] = __float2bfloat16(t[c][rr]);
}

// ---------------- precompute parity-effective 2x2 kernels: wg[ic*OC+oc][s*4+j] -----------------------
__global__ void k_weff(const float* __restrict__ w, float* __restrict__ wg, int IC, int OC)
{
    const int idx = blockIdx.x * 256 + threadIdx.x;
    if (idx >= IC * OC) return;
    const float* wp = w + (size_t)idx * 9;
    float wl[9];
#pragma unroll
    for (int k = 0; k < 9; ++k) wl[k] = wp[k];
    const float rm_[2][2][3] = {{{0.f,1.f,1.f},{1.f,0.f,0.f}},
                                {{0.f,0.f,1.f},{1.f,1.f,0.f}}};
    float* o = wg + (size_t)idx * 16;
#pragma unroll
    for (int py = 0; py < 2; ++py)
#pragma unroll
    for (int px = 0; px < 2; ++px)
#pragma unroll
    for (int r = 0; r < 2; ++r)
#pragma unroll
    for (int c = 0; c < 2; ++c) {
        float s = 0.f;
#pragma unroll
        for (int ky = 0; ky < 3; ++ky)
#pragma unroll
        for (int kx = 0; kx < 3; ++kx)
            s += rm_[py][r][ky] * rm_[px][c][kx] * wl[ky * 3 + kx];
        o[(r * 2 + c) * 4 + (py * 2 + px)] = s;     // transposed: [src][j]
    }
}

// ---------------- Bt4[s][n=oc*4+j][ic(pad32)] bf16 from weff (stage-4 MFMA B matrix) -----------------
__global__ void k_weffB(const float* __restrict__ weff, __hip_bfloat16* __restrict__ Bt4)
{
    const int t = blockIdx.x * 256 + threadIdx.x;   // t = s*128 + n
    if (t >= 512) return;
    const int s = t >> 7, n = t & 127;
    const int oc = n >> 2, j = n & 3;
    ushort* dst = (ushort*)Bt4 + (size_t)t * 32;
#pragma unroll
    for (int icb = 0; icb < 4; ++icb) {
        short8 pk;
#pragma unroll
        for (int u = 0; u < 8; ++u) {
            const int ic = icb * 8 + u;
            const float v = (ic < 25 && oc < 25) ? weff[((size_t)ic * 25 + oc) * 16 + s * 4 + j] : 0.f;
            pk[u] = f2bf_s(v);
        }
        *(short8*)(dst + icb * 8) = pk;
    }
}

// ---------------- border zero (border cells ONLY) -----------------------------------------------------
__global__ void k_zero_border(float* __restrict__ buf, int PH, int PW, int IR0, int IR1, int IC0, int IC1)
{
    float* plane = buf + (size_t)blockIdx.x * PH * PW;
    const int tid = threadIdx.x;
    const int topN = IR0 * PW;
    for (int i = tid; i < topN; i += 256) plane[i] = 0.f;
    const int botBase = IR1 * PW, botN = (PH - IR1) * PW;
    for (int i = tid; i < botN; i += 256) plane[botBase + i] = 0.f;
    const int rows = IR1 - IR0;
    const int wL = IC0, wR = PW - IC1, wLR = wL + wR;
    const int n = rows * wLR;
    for (int i = tid; i < n; i += 256) {
        const int r = i / wLR, c = i - r * wLR;
        const int col = (c < wL) ? c : (IC1 + c - wL);
        plane[(IR0 + r) * PW + col] = 0.f;
    }
}

// ---------------- d3p [64][25][130][66] f32 -> nhwc [64][130][66][32] bf16 (ch-pad 32) ----------------
__global__ void k_nhwc(const float* __restrict__ src, __hip_bfloat16* __restrict__ dst)
{
    const int idx = blockIdx.x * 256 + threadIdx.x;       // (b, p, q); 64*130*66 = 549120 exactly
    const int b = idx / 8580;
    const int rem = idx - b * 8580;
    const int p = rem / 66, q = rem - (rem / 66) * 66;
    const float* sp = src + ((size_t)b * 25 * 130 + p) * 66 + q;
    ushort* dp = (ushort*)dst + (size_t)idx * 32;
#pragma unroll
    for (int icb = 0; icb < 4; ++icb) {
        short8 pk;
#pragma unroll
        for (int u = 0; u < 8; ++u) {
            const int ic = icb * 8 + u;
            const float v = (ic < 25) ? sp[(size_t)ic * 130 * 66] : 0.f;
            pk[u] = f2bf_s(v);
        }
        *(short8*)(dp + icb * 8) = pk;
    }
}

// ---------------- rv = relu(rela_feats @ w_rela + b_rela) -> bf16 [32768][1024] ----------------------
// COALESCED-WRITE rewrite (r26 PMC: old layout stored 16B pieces at 128B stride -> 2.8x write
// amplification, 188MB for a 67MB buffer, 147us at 12% VALUBusy). New mapping: thread t covers cols
// (t&127)*8 of rows r0+2*(t>>7)+{0,1}; each wave's store = 1KB fully contiguous; 2 rows share weights.
__global__ void k_rv(const float* __restrict__ rela_feats, const float* __restrict__ w_rela,
                     const float* __restrict__ b_rela, __hip_bfloat16* __restrict__ rv)
{
    const int tid = threadIdx.x;
    const int r0 = blockIdx.x * 4;            // 8192 blocks x 4 rows
    const int rg = tid >> 7;                  // 0..1
    const int c  = (tid & 127) * 8;           // 0..1016
    __shared__ float rf[4][8];
    if (tid < 32) rf[tid >> 3][tid & 7] = rela_feats[(size_t)(r0 + (tid >> 3)) * 8 + (tid & 7)];
    __syncthreads();
    const int rowA = r0 + rg * 2;
    __hip_bfloat16* oA = rv + (size_t)rowA * 1024 + c;
    __hip_bfloat16* oB = oA + 1024;
    if (c < RNN_) {
        float a0[8], a1[8];
        const float4 b0 = *(const float4*)(b_rela + c);
        const float4 b1 = *(const float4*)(b_rela + c + 4);
        a0[0] = b0.x; a0[1] = b0.y; a0[2] = b0.z; a0[3] = b0.w;
        a0[4] = b1.x; a0[5] = b1.y; a0[6] = b1.z; a0[7] = b1.w;
#pragma unroll
        for (int j = 0; j < 8; ++j) a1[j] = a0[j];
#pragma unroll
        for (int f = 0; f < 8; ++f) {
            const float4 w0 = *(const float4*)(w_rela + f * RNN_ + c);
            const float4 w1 = *(const float4*)(w_rela + f * RNN_ + c + 4);
            const float fA = rf[rg * 2][f];
            const float fB = rf[rg * 2 + 1][f];
            a0[0] += fA * w0.x; a0[1] += fA * w0.y; a0[2] += fA * w0.z; a0[3] += fA * w0.w;
            a0[4] += fA * w1.x; a0[5] += fA * w1.y; a0[6] += fA * w1.z; a0[7] += fA * w1.w;
            a1[0] += fB * w0.x; a1[1] += fB * w0.y; a1[2] += fB * w0.z; a1[3] += fB * w0.w;
            a1[4] += fB * w1.x; a1[5] += fB * w1.y; a1[6] += fB * w1.z; a1[7] += fB * w1.w;
        }
        short8 pkA, pkB;
#pragma unroll
        for (int j = 0; j < 8; ++j) {
            pkA[j] = f2bf_s(fmaxf(a0[j], 0.f));
            pkB[j] = f2bf_s(fmaxf(a1[j], 0.f));
        }
        *(short8*)oA = pkA;
        *(short8*)oB = pkB;
    } else {
        const short8 z = {0,0,0,0,0,0,0,0};
        *(short8*)oA = z;
        *(short8*)oB = z;
    }
}

// ---------------- MFMA bf16 GEMM: C = A[M][Kpad] @ Bt[Npad][Kpad]^T, 128x128 tile, BK=64 --------------
template<int MODE>
__global__ __launch_bounds__(256)
void mfma_gemm(const __hip_bfloat16* __restrict__ A, const __hip_bfloat16* __restrict__ Bt, int Kpad,
               const float* __restrict__ bias, int ldc, int ncols,
               __hip_bfloat16* __restrict__ outB,
               const __half* __restrict__ P13H, const int* __restrict__ edges,
               const float* __restrict__ masks, int lgNT)
{
    __shared__ __align__(16) ushort smem[16384];    // 32 KB: lA0|lA1|lB0|lB1 (4x8KB) | ftile overlay
    ushort* lA0 = smem;
    ushort* lA1 = smem + 4096;
    ushort* lB0 = smem + 8192;
    ushort* lB1 = smem + 12288;
    const int tid = threadIdx.x;
    const int l = (blockIdx.x & 7) * ((int)gridDim.x >> 3) + ((int)blockIdx.x >> 3);
    const int n0 = (l & ((1 << lgNT) - 1)) * 128;
    const int m0 = (l >> lgNT) * 128;
    const int wave = tid >> 6, lane = tid & 63;
    const int wr = wave >> 1, wc = wave & 1;
    const int lr = lane >> 4, lc = lane & 15;
    const int lrow = lane >> 2;          // 0..15: row within wave's 16-row chunk
    const int lcol = (lane & 3) * 8;     // ushort offset of 16B chunk
    f32x4 acc[4][4];
#pragma unroll
    for (int i = 0; i < 4; ++i)
#pragma unroll
        for (int j = 0; j < 4; ++j) acc[i][j] = (f32x4){0.f, 0.f, 0.f, 0.f};

    for (int k0 = 0; k0 < Kpad; k0 += 64) {
        __syncthreads();                 // previous iter's ds_reads done before overwrite
#pragma unroll
        for (int j = 0; j < 2; ++j) {
            const int rbase = j * 64 + wave * 16;
            GLOAD_LDS16(A  + (size_t)(m0 + rbase + lrow) * Kpad + k0 + lcol,      &lA0[rbase * 32]);
            GLOAD_LDS16(A  + (size_t)(m0 + rbase + lrow) * Kpad + k0 + 32 + lcol, &lA1[rbase * 32]);
            GLOAD_LDS16(Bt + (size_t)(n0 + rbase + lrow) * Kpad + k0 + lcol,      &lB0[rbase * 32]);
            GLOAD_LDS16(Bt + (size_t)(n0 + rbase + lrow) * Kpad + k0 + 32 + lcol, &lB1[rbase * 32]);
        }
        __syncthreads();                 // drains vmcnt: both halves ready
#pragma unroll
        for (int h = 0; h < 2; ++h) {
            const ushort* hA = h ? lA1 : lA0;
            const ushort* hB = h ? lB1 : lB0;
            short8 af[4], bfr[4];
#pragma unroll
            for (int mi = 0; mi < 4; ++mi)
                af[mi] = *(const short8*)&hA[(wr * 64 + mi * 16 + lc) * 32 + lr * 8];
#pragma unroll
            for (int ni = 0; ni < 4; ++ni)
                bfr[ni] = *(const short8*)&hB[(wc * 64 + ni * 16 + lc) * 32 + lr * 8];
#pragma unroll
            for (int mi = 0; mi < 4; ++mi)
#pragma unroll
                for (int ni = 0; ni < 4; ++ni)
                    acc[mi][ni] = __builtin_amdgcn_mfma_f32_16x16x32_bf16(af[mi], bfr[ni], acc[mi][ni], 0, 0, 0);
        }
    }

    // ---------------- LDS-remap epilogue ----------------
    float* ftile = (float*)smem;         // [32][136] f32 (17408 B <= 32 KB)
    const int erow = tid >> 3;           // 0..31
    const int ecol0 = (tid & 7) * 16;    // 0..112
#pragma unroll
    for (int mi = 0; mi < 4; ++mi) {
        __syncthreads();                 // protect prior phase reads
#pragma unroll
        for (int ni = 0; ni < 4; ++ni) {
            const int colL = wc * 64 + ni * 16 + lc;
#pragma unroll
            for (int r = 0; r < 4; ++r)
                ftile[(wr * 16 + lr * 4 + r) * 136 + colL] = acc[mi][ni][r];
        }
        __syncthreads();
        const int rowL = (erow < 16) ? (mi * 16 + erow) : (64 + mi * 16 + (erow - 16));
        const int grow = m0 + rowL;
        const int gcol = n0 + ecol0;
        float v[16];
#pragma unroll
        for (int j = 0; j < 4; ++j) {
            const f32x4 t4 = *(const f32x4*)&ftile[erow * 136 + ecol0 + j * 4];
            v[j*4+0] = t4[0]; v[j*4+1] = t4[1]; v[j*4+2] = t4[2]; v[j*4+3] = t4[3];
        }
        if (MODE == 0) {
            short8 pk0, pk1;
#pragma unroll
            for (int j = 0; j < 16; ++j) {
                const int c = gcol + j;
                const float bb = (c < ncols) ? bias[c] : 0.f;
                const short s = f2bf_s(fmaxf(v[j] + bb, 0.f));
                if (j < 8) pk0[j] = s; else pk1[j - 8] = s;
            }
            *(short8*)(outB + (size_t)grow * 1024 + gcol)     = pk0;
            *(short8*)(outB + (size_t)grow * 1024 + gcol + 8) = pk1;
        } else if (MODE == 1) {
            __half* outH = (__half*)outB;
            if (gcol + 15 < ncols) {
                __half h[16];
#pragma unroll
                for (int j = 0; j < 16; ++j) h[j] = __float2half(v[j]);
                *(short8*)(outH + (size_t)grow * ldc + gcol)     = *(short8*)&h[0];
                *(short8*)(outH + (size_t)grow * ldc + gcol + 8) = *(short8*)&h[8];
            } else {
#pragma unroll
                for (int j = 0; j < 16; ++j) {
                    const int c = gcol + j;
                    if (c < ncols) outH[(size_t)grow * ldc + c] = __float2half(v[j]);
                }
            }
        } else {
            const int b = grow >> 9;           // NR = 512
            const int e0 = edges[grow * 2], e1 = edges[grow * 2 + 1];
            const float mk = masks[grow];
            const __half* p0 = P13H + (size_t)(b * NO_ + e0) * 2048 + gcol;
            const __half* p1 = P13H + (size_t)(b * NO_ + e1) * 2048 + 1024 + gcol;
            if (gcol + 15 < ncols) {
                __half h0[16], h1[16];
                *(short8*)&h0[0] = *(const short8*)p0;  *(short8*)&h0[8] = *(const short8*)(p0 + 8);
                *(short8*)&h1[0] = *(const short8*)p1;  *(short8*)&h1[8] = *(const short8*)(p1 + 8);
                float bb[16];
#pragma unroll
                for (int j = 0; j < 4; ++j) {
                    const float4 b4 = *(const float4*)(bias + gcol + j * 4);
                    bb[j*4+0] = b4.x; bb[j*4+1] = b4.y; bb[j*4+2] = b4.z; bb[j*4+3] = b4.w;
                }
                short8 pk0, pk1;
#pragma unroll
                for (int j = 0; j < 16; ++j) {
                    float val = v[j] + bb[j] + __half2float(h0[j]) + __half2float(h1[j]);
                    const short s = f2bf_s(fmaxf(val, 0.f) * mk);
                    if (j < 8) pk0[j] = s; else pk1[j - 8] = s;
                }
                *(short8*)(outB + (size_t)grow * RNN_ + gcol)     = pk0;
                *(short8*)(outB + (size_t)grow * RNN_ + gcol + 8) = pk1;
            } else if (gcol < ncols) {
#pragma unroll
                for (int j = 0; j < 16; ++j) {
                    const int c = gcol + j;
                    if (c < ncols) {
                        float val = v[j] + bias[c] + __half2float(p0[j]) + __half2float(p1[j]);
                        outB[(size_t)grow * RNN_ + c] = __float2bfloat16(fmaxf(val, 0.f) * mk);
                    }
                }
            }
        }
    }
}

// ---------------- stage-4 ConvT as MFMA GEMM over NHWC bf16 -------------------------------------------
__global__ __launch_bounds__(256)
void mfma_conv4(const __hip_bfloat16* __restrict__ nhwc, const __hip_bfloat16* __restrict__ Bt4,
                const float* __restrict__ bias, float* __restrict__ xout)
{
    __shared__ __align__(16) ushort smem[16384];    // 32 KB: A[4][128][32] | ftile overlay
    const int tid = threadIdx.x;
    const int m0 = (int)blockIdx.x * 128;
    const int wave = tid >> 6, lane = tid & 63;
    const int wr = wave >> 1, wc = wave & 1;
    const int lr = lane >> 4, lc = lane & 15;
    const int lrow = lane >> 2;
    const int lcol = (lane & 3) * 8;
    f32x4 acc[4][4];
#pragma unroll
    for (int i = 0; i < 4; ++i)
#pragma unroll
        for (int j = 0; j < 4; ++j) acc[i][j] = (f32x4){0.f, 0.f, 0.f, 0.f};

#pragma unroll
    for (int s = 0; s < 4; ++s) {
        const int sr = s >> 1, sc = s & 1;
#pragma unroll
        for (int j = 0; j < 2; ++j) {
            const int rbase = j * 64 + wave * 16;
            const int row = m0 + rbase + lrow;
            const int b = row >> 13, a = (row >> 6) & 127, g = row & 63;
            GLOAD_LDS16(nhwc + ((size_t)(b * 130 + a + sr) * 66 + (g + 1 + sc)) * 32 + lcol,
                        &smem[s * 4096 + rbase * 32]);
        }
    }
    __syncthreads();                     // drains vmcnt: all 4 shift-tiles ready
#pragma unroll
    for (int s = 0; s < 4; ++s) {
        const ushort* lA = &smem[s * 4096];
        short8 af[4], bfr[4];
#pragma unroll
        for (int mi = 0; mi < 4; ++mi)
            af[mi] = *(const short8*)&lA[(wr * 64 + mi * 16 + lc) * 32 + lr * 8];
#pragma unroll
        for (int ni = 0; ni < 4; ++ni)
            bfr[ni] = *(const short8*)((const ushort*)Bt4 +
                      ((size_t)(s * 128 + wc * 64 + ni * 16 + lc)) * 32 + lr * 8);
#pragma unroll
        for (int mi = 0; mi < 4; ++mi)
#pragma unroll
            for (int ni = 0; ni < 4; ++ni)
                acc[mi][ni] = __builtin_amdgcn_mfma_f32_16x16x32_bf16(af[mi], bfr[ni], acc[mi][ni], 0, 0, 0);
    }

    // ---------------- epilogue: remap + sigmoid + NCHW store ----------------
    float* ftile = (float*)smem;         // [32][136] f32
    const int erow = tid >> 3;
    const int ecol0 = (tid & 7) * 16;    // 16 cols = 4 oc x 4 j
#pragma unroll
    for (int mi = 0; mi < 4; ++mi) {
        __syncthreads();
#pragma unroll
        for (int ni = 0; ni < 4; ++ni) {
            const int colL = wc * 64 + ni * 16 + lc;
#pragma unroll
            for (int r = 0; r < 4; ++r)
                ftile[(wr * 16 + lr * 4 + r) * 136 + colL] = acc[mi][ni][r];
        }
        __syncthreads();
        const int rowL = (erow < 16) ? (mi * 16 + erow) : (64 + mi * 16 + (erow - 16));
        const int grow = m0 + rowL;
        const int b = grow >> 13, a = (grow >> 6) & 127, g = grow & 63;
        float v[16];
#pragma unroll
        for (int j = 0; j < 4; ++j) {
            const f32x4 t4 = *(const f32x4*)&ftile[erow * 136 + ecol0 + j * 4];
            v[j*4+0] = t4[0]; v[j*4+1] = t4[1]; v[j*4+2] = t4[2]; v[j*4+3] = t4[3];
        }
        if (a < 127 && g < 63) {
#pragma unroll
            for (int k = 0; k < 4; ++k) {
                const int oc = (ecol0 >> 2) + k;
                if (oc < 25) {
                    const float bv = bias[oc];
                    const float j0 = 1.f / (1.f + expf(-(v[k*4+0] + bv)));
                    const float j1 = 1.f / (1.f + expf(-(v[k*4+1] + bv)));
                    const float j2 = 1.f / (1.f + expf(-(v[k*4+2] + bv)));
                    const float j3 = 1.f / (1.f + expf(-(v[k*4+3] + bv)));
                    float* dp = xout + ((size_t)(b * 25 + oc) * 254 + 2 * a) * 126 + 2 * g;
                    *reinterpret_cast<float2*>(dp)       = make_float2(j0, j1);
                    *reinterpret_cast<float2*>(dp + 126) = make_float2(j2, j3);
                }
            }
        }
    }
}

// ---------------- split-K skinny GEMM (M=64): part[kz][64][N] = A[64][kz-chunk] @ W[chunk][N] ---------
__global__ void k_gemm_sk(const float* __restrict__ A, const float* __restrict__ W,
                          float* __restrict__ part, int N, int K, int ldw, int Kc)
{
    __shared__ float As[16][68];
    __shared__ float Ws[16][68];
    const int tid = threadIdx.x;
    const int n0 = blockIdx.x * 64;
    const int kz = blockIdx.y;
    const int kstart = kz * Kc;
    const int kend = (kstart + Kc < K) ? (kstart + Kc) : K;
    const int ty = tid >> 4, tx = tid & 15;
    float acc[4][4] = {};
    for (int k0 = kstart; k0 < kend; k0 += 16) {
#pragma unroll
        for (int i = 0; i < 4; ++i) {
            int lin = i * 256 + tid;
            int r = lin >> 4, kk = lin & 15;
            int k = k0 + kk;
            As[kk][r] = (k < kend) ? A[(size_t)r * K + k] : 0.f;
            int kr = lin >> 6, c = lin & 63;
            int kw = k0 + kr, cc = n0 + c;
            Ws[kr][c] = (kw < kend && cc < N) ? W[(size_t)kw * ldw + cc] : 0.f;
        }
        __syncthreads();
#pragma unroll
        for (int kk = 0; kk < 16; ++kk) {
            const float4 av = *reinterpret_cast<const float4*>(&As[kk][ty * 4]);
            const float4 wv = *reinterpret_cast<const float4*>(&Ws[kk][tx * 4]);
            const float a4[4] = {av.x, av.y, av.z, av.w};
            const float w4[4] = {wv.x, wv.y, wv.z, wv.w};
#pragma unroll
            for (int i = 0; i < 4; ++i)
#pragma unroll
                for (int j = 0; j < 4; ++j) acc[i][j] += a4[i] * w4[j];
        }
        __syncthreads();
    }
#pragma unroll
    for (int i = 0; i < 4; ++i) {
        const int row = ty * 4 + i;
#pragma unroll
        for (int j = 0; j < 4; ++j) {
            const int col = n0 + tx * 4 + j;
            if (col < N)
                part[((size_t)kz * 64 + row) * N + col] = acc[i][j];
        }
    }
}

// ---------------- reduce split-K partials + bias + act -------------------------------------------------
__global__ void k_sk_reduce(const float* __restrict__ part, const float* __restrict__ bias,
                            float* __restrict__ out, int N, int KS, int ldo, int act)
{
    const int idx = blockIdx.x * 256 + threadIdx.x;
    if (idx >= 64 * N) return;
    const int row = idx / N, col = idx - row * N;
    float s = bias[col];
    for (int z = 0; z < KS; ++z) s += part[((size_t)z * 64 + row) * N + col];
    if (act) s = fmaxf(s, 0.f);
    out[(size_t)row * ldo + col] = s;
}

// ---------------- attention dot: dot[row] = tanh(feats[row,:]) . w_att + b (vectorized bf16) ----------
__global__ void k_att_dot(const __hip_bfloat16* __restrict__ feats, const float* __restrict__ w_att,
                          const float* __restrict__ b_att, float* __restrict__ dot, int D, int ld)
{
    const int row = blockIdx.x;
    const int tid = threadIdx.x;   // 256
    const int c = tid * 4;
    float s = 0.f;
    if (c < D) {
        const ushort4 v = *(const ushort4*)(feats + (size_t)row * ld + c);
        const float4 wv = *(const float4*)(w_att + c);
        s  = tanhf(bf2f(v.x)) * wv.x;
        s += tanhf(bf2f(v.y)) * wv.y;
        s += tanhf(bf2f(v.z)) * wv.z;
        s += tanhf(bf2f(v.w)) * wv.w;
    }
#pragma unroll
    for (int o = 32; o > 0; o >>= 1) s += __shfl_down(s, o, 64);
    __shared__ float part[4];
    if ((tid & 63) == 0) part[tid >> 6] = s;
    __syncthreads();
    if (tid == 0) dot[row] = part[0] + part[1] + part[2] + part[3] + b_att[0];
}

// ---------------- masked, renormalized softmax weights (block per batch, blockDim == Nn) -------------
__global__ void k_softmax(const float* __restrict__ dot, const float* __restrict__ mask,
                          float* __restrict__ wgt, int Nn)
{
    const int b = blockIdx.x, tid = threadIdx.x;
    __shared__ float red[512];
    float v = dot[b * Nn + tid];
    red[tid] = v; __syncthreads();
    for (int s = Nn >> 1; s > 0; s >>= 1) { if (tid < s) red[tid] = fmaxf(red[tid], red[tid + s]); __syncthreads(); }
    float mx = red[0]; __syncthreads();
    float e = expf(v - mx);
    red[tid] = e; __syncthreads();
    for (int s = Nn >> 1; s > 0; s >>= 1) { if (tid < s) red[tid] += red[tid + s]; __syncthreads(); }
    float sm = red[0]; __syncthreads();
    float w0 = (e / sm) * mask[b * Nn + tid];
    red[tid] = w0; __syncthreads();
    for (int s = Nn >> 1; s > 0; s >>= 1) { if (tid < s) red[tid] += red[tid + s]; __syncthreads(); }
    wgt[b * Nn + tid] = w0 / red[0];
}

// ---------------- weighted sum: out[b, off+d0..3] = sum_n wgt[b,n]*feats[b,n,d] (vectorized) ----------
__global__ void k_wsum(const __hip_bfloat16* __restrict__ feats, const float* __restrict__ wgt,
                       float* __restrict__ out, int Nn, int D, int ld, int ldo, int off)
{
    const int b = blockIdx.x;
    const int tid = threadIdx.x;     // 256
    __shared__ float wl[512];
    for (int i = tid; i < Nn; i += 256) wl[i] = wgt[b * Nn + i];
    __syncthreads();
    const int d0 = tid * 4;
    if (d0 >= D) return;
    float a0 = 0.f, a1 = 0.f, a2 = 0.f, a3 = 0.f;
    const __hip_bfloat16* fp = feats + (size_t)b * Nn * ld + d0;
#pragma unroll 8
    for (int n = 0; n < Nn; ++n) {
        const ushort4 v = *(const ushort4*)(fp + (size_t)n * ld);
        const float w = wl[n];
        a0 += w * bf2f(v.x); a1 += w * bf2f(v.y);
        a2 += w * bf2f(v.z); a3 += w * bf2f(v.w);
    }
    *(float4*)(out + (size_t)b * ldo + off + d0) = make_float4(a0, a1, a2, a3);
}

// ---------------- parity up2+ConvT: 1 quad/thread, 5 oc/thread, PACKED f32, SGPR weights --------------
__global__ void k_convt5(const float* __restrict__ src, const float* __restrict__ wg,
                         const float* __restrict__ bias, float* __restrict__ dst,
                         int IC, int OC, int SH, int SW, int act,
                         int dro, int dco, int DPH, int DPW)
{
    const int QH = SH + 1, QW = SW + 1;
    const int ocg = blockIdx.y, b = blockIdx.z;
    const int tid = threadIdx.x;
    const int p = blockIdx.x * blockDim.x + tid;
    if (p >= QH * QW) return;
    const int a = p / QW, g = p % QW;
    const bool rm = (a > 0), rp = (a < SH);
    const bool cm = (g > 0), cp = (g < SW);
    f32x2v acc2[5][2];
#pragma unroll
    for (int ol = 0; ol < 5; ++ol) { acc2[ol][0] = (f32x2v){0.f, 0.f}; acc2[ol][1] = (f32x2v){0.f, 0.f}; }
    const float* sb = src + (size_t)(b * IC) * SH * SW;
    const int base = (a - 1) * SW + (g - 1);
    for (int ic = 0; ic < IC; ++ic) {
        const float* s = sb + (size_t)ic * SH * SW;
        const float s00 = (rm && cm) ? s[base] : 0.f;
        const float s01 = (rm && cp) ? s[base + 1] : 0.f;
        const float s10 = (rp && cm) ? s[base + SW] : 0.f;
        const float s11 = (rp && cp) ? s[base + SW + 1] : 0.f;
        const f32x2v b0 = {s00, s00}, b1 = {s01, s01}, b2 = {s10, s10}, b3 = {s11, s11};
        const float* wf = wg + ((size_t)ic * OC + ocg * 5) * 16;   // wave-uniform
#pragma unroll
        for (int ol = 0; ol < 5; ++ol) {
            const f32x4v w0 = *(const f32x4v*)(wf + ol * 16 + 0);
            const f32x4v w1 = *(const f32x4v*)(wf + ol * 16 + 4);
            const f32x4v w2 = *(const f32x4v*)(wf + ol * 16 + 8);
            const f32x4v w3 = *(const f32x4v*)(wf + ol * 16 + 12);
            acc2[ol][0] += b0 * __builtin_shufflevector(w0, w0, 0, 1);
            acc2[ol][0] += b1 * __builtin_shufflevector(w1, w1, 0, 1);
            acc2[ol][0] += b2 * __builtin_shufflevector(w2, w2, 0, 1);
            acc2[ol][0] += b3 * __builtin_shufflevector(w3, w3, 0, 1);
            acc2[ol][1] += b0 * __builtin_shufflevector(w0, w0, 2, 3);
            acc2[ol][1] += b1 * __builtin_shufflevector(w1, w1, 2, 3);
            acc2[ol][1] += b2 * __builtin_shufflevector(w2, w2, 2, 3);
            acc2[ol][1] += b3 * __builtin_shufflevector(w3, w3, 2, 3);
        }
    }
#pragma unroll
    for (int ol = 0; ol < 5; ++ol) {
        const int oc = ocg * 5 + ol;
        const float bv = bias[oc];
        float a00 = acc2[ol][0].x + bv, a01 = acc2[ol][0].y + bv;
        float a10 = acc2[ol][1].x + bv, a11 = acc2[ol][1].y + bv;
        if (act == 1) {
            a00 = fmaxf(a00, 0.f); a01 = fmaxf(a01, 0.f);
            a10 = fmaxf(a10, 0.f); a11 = fmaxf(a11, 0.f);
        } else {
            a00 = 1.f / (1.f + expf(-a00)); a01 = 1.f / (1.f + expf(-a01));
            a10 = 1.f / (1.f + expf(-a10)); a11 = 1.f / (1.f + expf(-a11));
        }
        float* dp = dst + ((size_t)(b * OC + oc) * DPH + 2 * a + dro) * DPW + 2 * g + dco;
        *reinterpret_cast<float2*>(dp)       = make_float2(a00, a01);
        *reinterpret_cast<float2*>(dp + DPW) = make_float2(a10, a11);
    }
}

// ---------------- parity up2+ConvT: 2 VERTICAL quads x 5 oc, SCALAR FMA, SGPR weights -----------------
// NO-BOUNDS variant (padded src). Stage 3 only (stage 4 is mfma_conv4 now).
__global__ void k_convtv(const float* __restrict__ src, int SPP, int SPW,
                         const float* __restrict__ wg,
                         const float* __restrict__ bias, float* __restrict__ dst,
                         int IC, int OC, int QH, int QW, int act, int LG,
                         int dro, int dco, int DPH, int DPW)
{
    const int ocg = blockIdx.y, b = blockIdx.z;
    const int tid = threadIdx.x;
    const int g = tid & ((1 << LG) - 1);
    const int a0 = blockIdx.x * ((256 >> LG) * 2) + (tid >> LG) * 2;
    if (g >= QW || a0 >= QH) return;
    float acc[5][2][4];
#pragma unroll
    for (int ol = 0; ol < 5; ++ol)
#pragma unroll
        for (int q = 0; q < 2; ++q)
#pragma unroll
            for (int j = 0; j < 4; ++j) acc[ol][q][j] = 0.f;
    const float* sb = src + (size_t)(b * IC) * SPP;
    const int rbase = a0 * SPW + g + 1;
    for (int ic = 0; ic < IC; ++ic) {
        const float* s = sb + (size_t)ic * SPP;
        float sv[3][2];
#pragma unroll
        for (int i = 0; i < 3; ++i) {
            sv[i][0] = s[rbase + i * SPW];
            sv[i][1] = s[rbase + i * SPW + 1];
        }
        const float* wf = wg + ((size_t)ic * OC + ocg * 5) * 16;   // wave-uniform (SGPR operands)
#pragma unroll
        for (int ol = 0; ol < 5; ++ol) {
#pragma unroll
            for (int q = 0; q < 2; ++q) {
#pragma unroll
                for (int j = 0; j < 4; ++j) {
                    acc[ol][q][j] += sv[q][0]     * wf[ol * 16 +  0 + j];
                    acc[ol][q][j] += sv[q][1]     * wf[ol * 16 +  4 + j];
                    acc[ol][q][j] += sv[q + 1][0] * wf[ol * 16 +  8 + j];
                    acc[ol][q][j] += sv[q + 1][1] * wf[ol * 16 + 12 + j];
                }
            }
        }
    }
    const bool q1ok = (a0 + 1 < QH);
#pragma unroll
    for (int ol = 0; ol < 5; ++ol) {
        const int oc = ocg * 5 + ol;
        const float bv = bias[oc];
        float* dp0 = dst + ((size_t)(b * OC + oc) * DPH + 2 * a0 + dro) * DPW + 2 * g + dco;
#pragma unroll
        for (int q = 0; q < 2; ++q) {
            if (q == 1 && !q1ok) continue;
            float v0 = acc[ol][q][0] + bv, v1 = acc[ol][q][1] + bv;
            float v2 = acc[ol][q][2] + bv, v3 = acc[ol][q][3] + bv;
            if (act == 1) {
                v0 = fmaxf(v0, 0.f); v1 = fmaxf(v1, 0.f);
                v2 = fmaxf(v2, 0.f); v3 = fmaxf(v3, 0.f);
            } else {
                v0 = 1.f / (1.f + expf(-v0)); v1 = 1.f / (1.f + expf(-v1));
                v2 = 1.f / (1.f + expf(-v2)); v3 = 1.f / (1.f + expf(-v3));
            }
            float* dp = dp0 + q * 2 * DPW;
            *reinterpret_cast<float2*>(dp)       = make_float2(v0, v1);
            *reinterpret_cast<float2*>(dp + DPW) = make_float2(v2, v3);
        }
    }
}

extern "C" void kernel_launch(void* const* d_in, const int* in_sizes, int n_in,
                              void* d_out, int out_size, void* d_ws, size_t ws_size,
                              hipStream_t stream)
{
    const int*   obj_labels = (const int*)  d_in[0];
    const float* obj_masks  = (const float*)d_in[1];
    const float* rela_masks = (const float*)d_in[2];
    const int*   rela_edges = (const int*)  d_in[3];
    const float* rela_feats = (const float*)d_in[4];
    const float* box_feats  = (const float*)d_in[5];
    const float* emb_table  = (const float*)d_in[6];
    const float* w_objfeat  = (const float*)d_in[7];
    const float* b_objfeat  = (const float*)d_in[8];
    const float* w_cat      = (const float*)d_in[9];
    const float* b_cat      = (const float*)d_in[10];
    const float* w_obj      = (const float*)d_in[11];
    const float* b_obj      = (const float*)d_in[12];
    const float* w_rela     = (const float*)d_in[13];
    const float* b_rela     = (const float*)d_in[14];
    const float* w_gnn      = (const float*)d_in[15];
    const float* b_gnn      = (const float*)d_in[16];
    const float* w_att_obj  = (const float*)d_in[17];
    const float* b_att_obj  = (const float*)d_in[18];
    const float* w_att_rela = (const float*)d_in[19];
    const float* b_att_rela = (const float*)d_in[20];
    const float* w_read     = (const float*)d_in[21];
    const float* b_read     = (const float*)d_in[22];
    const float* w_fc       = (const float*)d_in[23];
    const float* b_fc       = (const float*)d_in[24];
    const float* wt1 = (const float*)d_in[25]; const float* bt1 = (const float*)d_in[26];
    const float* wt2 = (const float*)d_in[27]; const float* bt2 = (const float*)d_in[28];
    const float* wt3 = (const float*)d_in[29]; const float* bt3 = (const float*)d_in[30];
    const float* wt4 = (const float*)d_in[31]; const float* bt4 = (const float*)d_in[32];

    float* ws = (float*)d_ws;
    // layout (float units)
    __hip_bfloat16* objembB  = (__hip_bfloat16*)(ws);                  // [0, 524288)
    __hip_bfloat16* obj_vecsB= (__hip_bfloat16*)(ws + 524288);         // [524288, 4718592)
    __hip_bfloat16* w_objT   = (__hip_bfloat16*)(ws + 4718592);        // [4718592, 4784128)
    __hip_bfloat16* w1T      = (__hip_bfloat16*)(ws + 4784128);        // [4784128, 5308416)
    __hip_bfloat16* w3T      = (__hip_bfloat16*)(ws + 5308416);        // [5308416, 5832704)  (adjacent!)
    __hip_bfloat16* w2T      = (__hip_bfloat16*)(ws + 5832704);        // [5832704, 6356992)
    __half*         P13H     = (__half*)(ws + 6356992);                // 8192*2048 f16 = [6356992, 14745600)
    __hip_bfloat16* rvB      = (__hip_bfloat16*)(ws + 14745600);       // [14745600, 31522816)
    __hip_bfloat16* newRB    = (__hip_bfloat16*)(ws + 31522816);       // [31522816, 47906816)
    float* dot_obj = ws + 47906816;
    float* dot_rel = dot_obj + 8192;
    float* wgt_obj = dot_rel + 32768;
    float* wgt_rel = wgt_obj + 8192;
    float* a_cat   = wgt_rel + 32768;                                  // 64*2000 = 128000
    float* part_enc = a_cat + 128000;                                  // 524288
    float* part_fc  = part_enc + 524288;                               // 1376256 -> end 50,017,184
    float* weff1 = ws + 50017184;                                      // 12800
    float* weff2 = weff1 + 12800;                                      // 10000
    float* weff3 = weff2 + 10000;
    float* weff4 = weff3 + 10000;                                      // end 50,059,984
    __hip_bfloat16* Bt4 = (__hip_bfloat16*)(ws + 50059984);            // 4*128*32 bf16 = 8192 f -> 50,068,176
    // decoder aliases (P13H/rvB/newRB dead after attention): d1 unpadded; d2p/d3p zero-PADDED planes
    float* d0  = ws;                   // objembB region, dead after GEMM1
    float* d1  = ws + 6356992;         // [64][25][30][14] = 672,000 f
    float* d2p = ws + 7028992;         // [64][25][66][34] -> ends 10,619,392
    float* d3p = ws + 10619392;        // [64][25][130][66] -> ends 24,347,392
    __hip_bfloat16* nhwc4 = (__hip_bfloat16*)(ws + 24347392);          // [64][130][66][32] bf16 -> 33,133,312 (dead rvB/newRB)
    float* enc  = (float*)d_out;
    float* xout = (float*)d_out + 65536;

    // 0. weight transposes -> bf16; conv weff tables; stage-4 MFMA B matrix
    k_transpose<<<dim3(4, 32),  256, 0, stream>>>(w_obj, w_objT, 128, RNN_, RNN_, 128);
    k_transpose<<<dim3(32, 32), 256, 0, stream>>>(w_gnn,                      w1T, RNN_, RNN_, RNN_, 1024);
    k_transpose<<<dim3(32, 32), 256, 0, stream>>>(w_gnn + (size_t)2*RNN_*RNN_,w3T, RNN_, RNN_, RNN_, 1024);
    k_transpose<<<dim3(32, 32), 256, 0, stream>>>(w_gnn + (size_t)RNN_*RNN_,  w2T, RNN_, RNN_, RNN_, 1024);
    k_weff<<<dim3(4), 256, 0, stream>>>(wt1, weff1, 32, 25);
    k_weff<<<dim3(3), 256, 0, stream>>>(wt2, weff2, 25, 25);
    k_weff<<<dim3(3), 256, 0, stream>>>(wt3, weff3, 25, 25);
    k_weff<<<dim3(3), 256, 0, stream>>>(wt4, weff4, 25, 25);
    k_weffB<<<dim3(2), 256, 0, stream>>>(weff4, Bt4);
    // 1. object embeddings -> bf16
    k_obj_embed<<<dim3(8192), dim3(128), 0, stream>>>(obj_labels, box_feats, emb_table,
                                                      w_objfeat, b_objfeat, w_cat, b_cat, objembB);
    // 2. obj_vecs = relu(obj_embed @ w_obj + b) -> bf16 [8192][1024]   (lgNT=3)
    mfma_gemm<0><<<dim3(512), 256, 0, stream>>>(objembB, w_objT, 128, b_obj,
                                                0, RNN_, obj_vecsB, nullptr, nullptr, nullptr, 3);
    // 3. P13 = obj_vecs @ [W1 | W3] (merged, N=2048) -> f16 [8192][2048]  (lgNT=4)
    mfma_gemm<1><<<dim3(1024), 256, 0, stream>>>(obj_vecsB, w1T, 1024, nullptr,
                                                 2048, 2048, (__hip_bfloat16*)P13H, nullptr, nullptr, nullptr, 4);
    // 4. rv -> bf16 [32768][1024]  (coalesced-write rewrite)
    k_rv<<<dim3(8192), 256, 0, stream>>>(rela_feats, w_rela, b_rela, rvB);
    // 5. GNN: new_rela = relu(rv @ W2 + b + f16 P13 gathers) * mask -> bf16 [32768][1000]  (lgNT=3)
    mfma_gemm<2><<<dim3(2048), 256, 0, stream>>>(rvB, w2T, 1024, b_gnn,
                                                 0, RNN_, newRB, P13H, rela_edges, rela_masks, 3);
    // 6. attention dots
    k_att_dot<<<8192,  256, 0, stream>>>(obj_vecsB, w_att_obj,  b_att_obj,  dot_obj, RNN_, 1024);
    k_att_dot<<<32768, 256, 0, stream>>>(newRB,     w_att_rela, b_att_rela, dot_rel, RNN_, RNN_);
    // 7. softmax weights
    k_softmax<<<64, 128, 0, stream>>>(dot_obj, obj_masks,  wgt_obj, 128);
    k_softmax<<<64, 512, 0, stream>>>(dot_rel, rela_masks, wgt_rel, 512);
    // 8. attention pooling -> a_cat (64 x 2000)
    k_wsum<<<dim3(64), 256, 0, stream>>>(obj_vecsB, wgt_obj, a_cat, 128, RNN_, 1024, 2000, 0);
    k_wsum<<<dim3(64), 256, 0, stream>>>(newRB,     wgt_rel, a_cat, 512, RNN_, RNN_, 2000, RNN_);
    // 9. enc = relu(a_cat @ w_read + b) -> d_out  (split-K)
    k_gemm_sk<<<dim3(16, 8), 256, 0, stream>>>(a_cat, w_read, part_enc, DIM_, 2000, DIM_, 256);
    k_sk_reduce<<<dim3(256), 256, 0, stream>>>(part_enc, b_read, enc, DIM_, 8, DIM_, 1);
    // 10. fc: d0 = enc @ w_fc + b_fc  (split-K)
    k_gemm_sk<<<dim3(42, 8), 256, 0, stream>>>(enc, w_fc, part_fc, 2688, DIM_, 2688, 128);
    k_sk_reduce<<<dim3(672), 256, 0, stream>>>(part_fc, b_fc, d0, 2688, 8, 2688, 0);
    // 11. decoder: stages 1-3 as before; stage 4 via NHWC repack + MFMA GEMM
    k_zero_border<<<dim3(1600), 256, 0, stream>>>(d2p, 66, 34, 1, 63, 2, 32);
    k_zero_border<<<dim3(1600), 256, 0, stream>>>(d3p, 130, 66, 1, 127, 2, 64);
    k_convt5<<<dim3(1, 5, 64), 256, 0, stream>>>(d0, weff1, bt1, d1, 32, 25, 14, 6, 1, 0, 0, 30, 14);
    k_convt5<<<dim3(2, 5, 64), 256, 0, stream>>>(d1, weff2, bt2, d2p, 25, 25, 30, 14, 1, 1, 2, 66, 34);
    k_convtv<<<dim3(4, 5, 64), 256, 0, stream>>>(d2p, 66 * 34, 34, weff3, bt3, d3p,
                                                 25, 25, 63, 31, 1, 5, 1, 2, 130, 66);
    k_nhwc<<<dim3(2145), 256, 0, stream>>>(d3p, nhwc4);
    mfma_conv4<<<dim3(4096), 256, 0, stream>>>(nhwc4, Bt4, bt4, xout);
}